// Round 6
// baseline (280.752 us; speedup 1.0000x reference)
//
#include <hip/hip_runtime.h>

// SIZE = (D,H,W) = (160,192,160), B=2, C=2.
#define DD 160
#define HH 192
#define WW 160
#define SP (DD * HH * WW)
#define NB 2
#define NC 2

// Persistent blocks, 512 threads, 2 samples/thread, channel-split phases
// with DOUBLE-BUFFERED LDS (stage of next phase issued before compute of
// current phase). TZ=4 tile -> 26.4 KB/buffer -> 52.8 KB/block ->
// 3 blocks/CU (24 waves) while keeping the full pipeline.
#define TX 32
#define TY 8
#define TZ 4
#define RXW 40                 // x: [X0-4, X0+35]  supports dx in [-4,4)
#define RYH 15                 // y: [Y0-3, Y0+11]  supports dy in [-3,4)
#define RZD 11                 // z: [Z0-3, Z0+7]   supports dz in [-3,4)
#define REGC (RZD * RYH * RXW) // 6600 voxels; 26,400 B per buffer
#define NCHUNK (REGC / 4)      // 1650 4-voxel chunks
#define NITER 4                // ceil(1650/512)

#define NTX 5
#define NTY 24
#define NTZ 40
#define NTILES (NTX * NTY * NTZ * NB)   // 9600 tiles
#define TPX (NTILES / 8)                // 1200 tiles per XCD
#define NBLK 768                        // persistent: 3 blocks/CU
#define SLOTS (NBLK / 8)                // 96 slots per XCD

typedef float v2f __attribute__((ext_vector_type(2)));
typedef float v4f __attribute__((ext_vector_type(4)));

typedef const void __attribute__((address_space(1)))* gas_ptr;
typedef void __attribute__((address_space(3)))* las_ptr;

__device__ __forceinline__ v2f ld2_nt(const float* p) {
    return __builtin_nontemporal_load(reinterpret_cast<const v2f*>(p));
}
__device__ __forceinline__ void st2_nt(float* p, v2f v) {
    __builtin_nontemporal_store(v, reinterpret_cast<v2f*>(p));
}
__device__ __forceinline__ v2f ld2g(const float* p) {
    return *reinterpret_cast<const v2f*>(p);
}

// Rare fallback: displacement outside staged halo — full global trilinear,
// single channel. (~0.3% of samples.)
__device__ __forceinline__ float sample_global1(
    const float* __restrict__ s,
    int x, int y, int z, float dx, float dy, float dz)
{
    float sx = (float)x + dx, sy = (float)y + dy, sz = (float)z + dz;
    float xf = floorf(sx), yf = floorf(sy), zf = floorf(sz);
    float fx = sx - xf, fy = sy - yf, fz = sz - zf;
    int x0 = (int)xf, y0 = (int)yf, z0 = (int)zf;
    int x1 = x0 + 1, y1 = y0 + 1, z1 = z0 + 1;

    float wx0 = (x0 >= 0 && x0 < WW) ? (1.0f - fx) : 0.0f;
    float wx1 = (x1 >= 0 && x1 < WW) ? fx : 0.0f;
    float wy0 = (y0 >= 0 && y0 < HH) ? (1.0f - fy) : 0.0f;
    float wy1 = (y1 >= 0 && y1 < HH) ? fy : 0.0f;
    float wz0 = (z0 >= 0 && z0 < DD) ? (1.0f - fz) : 0.0f;
    float wz1 = (z1 >= 0 && z1 < DD) ? fz : 0.0f;

    int p  = min(max(x0, 0), WW - 2);
    int i0 = min(max(x0, 0), WW - 1) - p;
    int i1 = min(max(x1, 0), WW - 1) - p;
    int cy0 = min(max(y0, 0), HH - 1), cy1 = min(max(y1, 0), HH - 1);
    int cz0 = min(max(z0, 0), DD - 1), cz1 = min(max(z1, 0), DD - 1);

    int o00 = (cz0 * HH + cy0) * WW + p;
    int o01 = (cz0 * HH + cy1) * WW + p;
    int o10 = (cz1 * HH + cy0) * WW + p;
    int o11 = (cz1 * HH + cy1) * WW + p;

    v2f c00 = ld2g(s + o00);
    v2f c01 = ld2g(s + o01);
    v2f c10 = ld2g(s + o10);
    v2f c11 = ld2g(s + o11);

    #define PICK(v, i) ((i) ? (v).y : (v).x)
    float r;
    r  = (wz0 * wy0) * (wx0 * PICK(c00, i0) + wx1 * PICK(c00, i1));
    r += (wz0 * wy1) * (wx0 * PICK(c01, i0) + wx1 * PICK(c01, i1));
    r += (wz1 * wy0) * (wx0 * PICK(c10, i0) + wx1 * PICK(c10, i1));
    r += (wz1 * wy1) * (wx0 * PICK(c11, i0) + wx1 * PICK(c11, i1));
    #undef PICK
    return r;
}

// Stage one channel into one LDS buffer via direct global->LDS DMA.
// Chunk c lands at sbuf[4c] (layout identity: region idx of chunk c == 4c),
// so within a wave the LDS destination is base + lane*16 — exactly the
// global_load_lds constraint.
//
// EDGE NOTE (why no post-fix is needed): chunks are either fully in-volume
// (staged correctly) or fully out-of-volume (x: only lxc=0 at X0=0 /
// lxc=9 at X0=128; y/z: clamped rows). Out-of-volume region cells are ONLY
// ever read with zero weight — the wx/wy/wz masks in sample_lds test the
// *volume* coordinate, and padding_mode='zeros' means such cells never
// contribute. The clamp below exists solely to keep addresses in-bounds.
__device__ __forceinline__ void stage_channel(
    const float* __restrict__ cb, int X0, int Y0, int Z0, int tid, float* sbuf)
{
    #pragma unroll
    for (int i = 0; i < NITER; ++i) {
        int c = tid + i * 512;
        if (i < NITER - 1 || c < NCHUNK) {
            int lz  = c / 150;  int r2 = c - lz * 150;   // 150 = RYH*RXW/4
            int ly  = r2 / 10;  int lxc = r2 - ly * 10;  // 10 = RXW/4
            int mz = min(max(Z0 - 3 + lz, 0), DD - 1);
            int my = min(max(Y0 - 3 + ly, 0), HH - 1);
            int mx = min(max(X0 - 4 + lxc * 4, 0), WW - 4);  // 16B-aligned
            const float* g = cb + (mz * HH + my) * WW + mx;
            __builtin_amdgcn_global_load_lds(
                (gas_ptr)g, (las_ptr)(sbuf + 4 * c), 16, 0, 0);
        }
    }
}

// Trilinear sample of the single-channel staged region.
// INTERIOR: the whole region lies strictly inside the volume, so the
// boundary zero-weight masks are provably always-pass — skip them.
template<bool INTERIOR>
__device__ __forceinline__ float sample_lds(
    const float* __restrict__ sbuf,
    float lx, float ly, float lz, int rx0, int ry0, int rz0)
{
    float xf = floorf(lx), yf = floorf(ly), zf = floorf(lz);
    float fx = lx - xf, fy = ly - yf, fz = lz - zf;
    int ix = (int)xf, iy = (int)yf, iz = (int)zf;

    float wx0, wx1, wy0, wy1, wz0, wz1;
    if (INTERIOR) {
        wx0 = 1.0f - fx; wx1 = fx;
        wy0 = 1.0f - fy; wy1 = fy;
        wz0 = 1.0f - fz; wz1 = fz;
    } else {
        int vx0 = ix + rx0, vy0 = iy + ry0, vz0 = iz + rz0;
        wx0 = (vx0 >= 0  && vx0 < WW)     ? (1.0f - fx) : 0.0f;
        wx1 = (vx0 >= -1 && vx0 < WW - 1) ? fx          : 0.0f;
        wy0 = (vy0 >= 0  && vy0 < HH)     ? (1.0f - fy) : 0.0f;
        wy1 = (vy0 >= -1 && vy0 < HH - 1) ? fy          : 0.0f;
        wz0 = (vz0 >= 0  && vz0 < DD)     ? (1.0f - fz) : 0.0f;
        wz1 = (vz0 >= -1 && vz0 < DD - 1) ? fz          : 0.0f;
    }

    const float* pB = sbuf + (iz * RYH + iy) * RXW + ix;
    // Adjacent x0/x1 pairs -> ds_read2_b32.
    float A00 = pB[0],        B00 = pB[1];
    float A01 = pB[RXW],      B01 = pB[RXW + 1];
    const float* pC = pB + RYH * RXW;
    float A10 = pC[0],        B10 = pC[1];
    float A11 = pC[RXW],      B11 = pC[RXW + 1];

    float c00 = wx0 * A00 + wx1 * B00;
    float c01 = wx0 * A01 + wx1 * B01;
    float c10 = wx0 * A10 + wx1 * B10;
    float c11 = wx0 * A11 + wx1 * B11;
    float m0  = wy0 * c00 + wy1 * c01;
    float m1  = wy0 * c10 + wy1 * c11;
    return wz0 * m0 + wz1 * m1;
}

struct Geo {
    int X0, Y0, Z0;
    int x, y, z;          // this thread's global coords (x = first of 2)
    bool interior;        // region strictly inside the volume
    const float* sb;      // src channel-0 base for this batch
    const float* fp;      // flow pointer for this thread
    float* op;            // out pointer (channel 0) for this thread
};

__device__ __forceinline__ Geo decode_tile(
    int tl, const float* src, const float* flow, float* out,
    int xi, int yl, int zl)
{
    Geo g;
    int tx = tl % NTX;  int t2 = tl / NTX;
    int ty = t2 % NTY;  int t3 = t2 / NTY;
    int tz = t3 % NTZ;  int b  = t3 / NTZ;
    g.X0 = tx * TX; g.Y0 = ty * TY; g.Z0 = tz * TZ;
    g.interior = (tx >= 1) & (tx <= 3) &
                 (ty >= 1) & (ty <= 22) &
                 (tz >= 1) & (tz <= 38);
    g.x = g.X0 + xi; g.y = g.Y0 + yl; g.z = g.Z0 + zl;
    int go = (g.z * HH + g.y) * WW + g.x;
    g.sb = src + b * NC * SP;
    g.fp = flow + b * 3 * SP + go;
    g.op = out + b * NC * SP + go;
    return g;
}

// Compute 2 samples for one channel from LDS and store them.
template<bool INTERIOR>
__device__ __forceinline__ void compute_store(
    const float* __restrict__ sbuf, const Geo& g, int cofs,   // 0 or SP
    v2f dxv, v2f dyv, v2f dzv, int xi, int yl, int zl)
{
    const int rx0 = g.X0 - 4, ry0 = g.Y0 - 3, rz0 = g.Z0 - 3;
    float a[2];
    #pragma unroll
    for (int j = 0; j < 2; ++j) {
        float dx = dxv[j], dy = dyv[j], dz = dzv[j];
        bool inH = (dx >= -4.0f) & (dx < 4.0f) &
                   (dy >= -3.0f) & (dy < 4.0f) &
                   (dz >= -3.0f) & (dz < 4.0f);
        if (inH) {
            float lx = (float)(xi + j + 4) + dx;
            float ly = (float)(yl + 3) + dy;
            float lz = (float)(zl + 3) + dz;
            a[j] = sample_lds<INTERIOR>(sbuf, lx, ly, lz, rx0, ry0, rz0);
        } else {
            a[j] = sample_global1(g.sb + cofs, g.x + j, g.y, g.z, dx, dy, dz);
        }
    }
    v2f o = {a[0], a[1]};
    st2_nt(g.op + cofs, o);
}

// 3 blocks/CU (LDS-capped at 52.8 KB) -> 6 waves/SIMD -> VGPR cap 85;
// natural usage ~52-70: no spill (watch WRITE_SIZE == 76,800 KB).
__global__ __launch_bounds__(512, 6) void st_warp_kernel(
    const float* __restrict__ src,   // [B, C, D, H, W]
    const float* __restrict__ flow,  // [B, 3, D, H, W]
    float* __restrict__ out)         // [B, C, D, H, W]
{
    __shared__ float sA[REGC];   // channel-0 buffer
    __shared__ float sB[REGC];   // channel-1 buffer   (52,800 B total)

    int u    = blockIdx.x;
    int xcd  = u & 7;            // XCD-chunked tile ranges
    int slot = u >> 3;           // 0..95 within XCD
    int tid  = threadIdx.x;

    int xi = (tid & 15) << 1;    // 0..30 step 2
    int rr = tid >> 4;           // 0..31
    int yl = rr & 7, zl = rr >> 3;   // y 0..7, z 0..3

    // Tiles for this block: tl0, tl0+96, ... (12 or 13 tiles).
    int nt = (TPX - slot + SLOTS - 1) / SLOTS;
    int tl = xcd * TPX + slot;

    // ---- Prologue: stage tile 0 / c0, load its flow ----
    Geo g = decode_tile(tl, src, flow, out, xi, yl, zl);
    stage_channel(g.sb, g.X0, g.Y0, g.Z0, tid, sA);
    v2f dxv = ld2_nt(g.fp);
    v2f dyv = ld2_nt(g.fp + SP);
    v2f dzv = ld2_nt(g.fp + 2 * SP);

    for (int t = 0; t < nt; ++t) {
        __syncthreads();     // drains vmcnt: sA(c0,t) staged; sB free

        // Issue c1 staging, then compute c0 — stage hides under compute.
        stage_channel(g.sb + SP, g.X0, g.Y0, g.Z0, tid, sB);
        if (g.interior)
            compute_store<true >(sA, g, 0, dxv, dyv, dzv, xi, yl, zl);
        else
            compute_store<false>(sA, g, 0, dxv, dyv, dzv, xi, yl, zl);

        __syncthreads();     // drains vmcnt: sB(c1,t) staged; sA free

        // Issue next tile's c0 staging + flow loads, then compute c1.
        bool more = (t + 1 < nt);          // block-uniform
        Geo gn = g;
        v2f nxv = dxv, nyv = dyv, nzv = dzv;
        if (more) {
            gn = decode_tile(tl + (t + 1) * SLOTS, src, flow, out, xi, yl, zl);
            stage_channel(gn.sb, gn.X0, gn.Y0, gn.Z0, tid, sA);
            nxv = ld2_nt(gn.fp);
            nyv = ld2_nt(gn.fp + SP);
            nzv = ld2_nt(gn.fp + 2 * SP);
        }
        if (g.interior)
            compute_store<true >(sB, g, SP, dxv, dyv, dzv, xi, yl, zl);
        else
            compute_store<false>(sB, g, SP, dxv, dyv, dzv, xi, yl, zl);

        g = gn; dxv = nxv; dyv = nyv; dzv = nzv;
    }
}

extern "C" void kernel_launch(void* const* d_in, const int* in_sizes, int n_in,
                              void* d_out, int out_size, void* d_ws, size_t ws_size,
                              hipStream_t stream) {
    const float* src  = (const float*)d_in[0];
    const float* flow = (const float*)d_in[1];
    float* out = (float*)d_out;

    st_warp_kernel<<<NBLK, 512, 0, stream>>>(src, flow, out);
}

// Round 7
// 279.219 us; speedup vs baseline: 1.0055x; 1.0055x over previous
//
#include <hip/hip_runtime.h>

// SIZE = (D,H,W) = (160,192,160), B=2, C=2.
#define DD 160
#define HH 192
#define WW 160
#define SP (DD * HH * WW)
#define NB 2
#define NC 2

// Persistent blocks, 1024 threads, 2 samples/thread, channel-split phases
// with DOUBLE-BUFFERED LDS (stage of next phase issued before compute of
// current phase). TZ=8 tile (4.39x staging amplification, R5-best) with
// 16-wave blocks: 2 blocks/CU x 16 waves = 32 waves/CU cap — 2x R5's
// latency-hiding at identical per-output staging/barrier cost.
#define TX 32
#define TY 8
#define TZ 8
#define RXW 40                 // x: [X0-4, X0+35]  supports dx in [-4,4)
#define RYH 15                 // y: [Y0-3, Y0+11]  supports dy in [-3,4)
#define RZD 15                 // z: [Z0-3, Z0+11]  supports dz in [-3,4)
#define REGC (RZD * RYH * RXW) // 9000 voxels; 36,000 B per buffer
#define NCHUNK (REGC / 4)      // 2250 4-voxel chunks
#define NITER 3                // ceil(2250/1024)
#define NTHR 1024

#define NTX 5
#define NTY 24
#define NTZ 20
#define NTILES (NTX * NTY * NTZ * NB)   // 4800 tiles
#define TPX (NTILES / 8)                // 600 tiles per XCD
#define NBLK 512                        // persistent: 2 blocks/CU
#define SLOTS (NBLK / 8)                // 64 slots per XCD

typedef float v2f __attribute__((ext_vector_type(2)));
typedef float v4f __attribute__((ext_vector_type(4)));

typedef const void __attribute__((address_space(1)))* gas_ptr;
typedef void __attribute__((address_space(3)))* las_ptr;

__device__ __forceinline__ v2f ld2_nt(const float* p) {
    return __builtin_nontemporal_load(reinterpret_cast<const v2f*>(p));
}
__device__ __forceinline__ void st2_nt(float* p, v2f v) {
    __builtin_nontemporal_store(v, reinterpret_cast<v2f*>(p));
}
__device__ __forceinline__ v2f ld2g(const float* p) {
    return *reinterpret_cast<const v2f*>(p);
}

// Rare fallback: displacement outside staged halo — full global trilinear,
// single channel. (~0.3% of samples.)
__device__ __forceinline__ float sample_global1(
    const float* __restrict__ s,
    int x, int y, int z, float dx, float dy, float dz)
{
    float sx = (float)x + dx, sy = (float)y + dy, sz = (float)z + dz;
    float xf = floorf(sx), yf = floorf(sy), zf = floorf(sz);
    float fx = sx - xf, fy = sy - yf, fz = sz - zf;
    int x0 = (int)xf, y0 = (int)yf, z0 = (int)zf;
    int x1 = x0 + 1, y1 = y0 + 1, z1 = z0 + 1;

    float wx0 = (x0 >= 0 && x0 < WW) ? (1.0f - fx) : 0.0f;
    float wx1 = (x1 >= 0 && x1 < WW) ? fx : 0.0f;
    float wy0 = (y0 >= 0 && y0 < HH) ? (1.0f - fy) : 0.0f;
    float wy1 = (y1 >= 0 && y1 < HH) ? fy : 0.0f;
    float wz0 = (z0 >= 0 && z0 < DD) ? (1.0f - fz) : 0.0f;
    float wz1 = (z1 >= 0 && z1 < DD) ? fz : 0.0f;

    int p  = min(max(x0, 0), WW - 2);
    int i0 = min(max(x0, 0), WW - 1) - p;
    int i1 = min(max(x1, 0), WW - 1) - p;
    int cy0 = min(max(y0, 0), HH - 1), cy1 = min(max(y1, 0), HH - 1);
    int cz0 = min(max(z0, 0), DD - 1), cz1 = min(max(z1, 0), DD - 1);

    int o00 = (cz0 * HH + cy0) * WW + p;
    int o01 = (cz0 * HH + cy1) * WW + p;
    int o10 = (cz1 * HH + cy0) * WW + p;
    int o11 = (cz1 * HH + cy1) * WW + p;

    v2f c00 = ld2g(s + o00);
    v2f c01 = ld2g(s + o01);
    v2f c10 = ld2g(s + o10);
    v2f c11 = ld2g(s + o11);

    #define PICK(v, i) ((i) ? (v).y : (v).x)
    float r;
    r  = (wz0 * wy0) * (wx0 * PICK(c00, i0) + wx1 * PICK(c00, i1));
    r += (wz0 * wy1) * (wx0 * PICK(c01, i0) + wx1 * PICK(c01, i1));
    r += (wz1 * wy0) * (wx0 * PICK(c10, i0) + wx1 * PICK(c10, i1));
    r += (wz1 * wy1) * (wx0 * PICK(c11, i0) + wx1 * PICK(c11, i1));
    #undef PICK
    return r;
}

// Stage one channel into one LDS buffer via direct global->LDS DMA.
// Chunk c lands at sbuf[4c] (layout identity: region idx of chunk c == 4c),
// so within a wave the LDS destination is base + lane*16 — exactly the
// global_load_lds constraint.
//
// EDGE NOTE (why no post-fix is needed): chunks are either fully in-volume
// (staged correctly) or fully out-of-volume (x: only lxc=0 at X0=0 /
// lxc=9 at X0=128; y/z: clamped rows). Out-of-volume region cells are ONLY
// ever read with zero weight — the wx/wy/wz masks in sample_lds test the
// *volume* coordinate, and padding_mode='zeros' means such cells never
// contribute. The clamp below exists solely to keep addresses in-bounds.
__device__ __forceinline__ void stage_channel(
    const float* __restrict__ cb, int X0, int Y0, int Z0, int tid, float* sbuf)
{
    #pragma unroll
    for (int i = 0; i < NITER; ++i) {
        int c = tid + i * NTHR;
        if (i < NITER - 1 || c < NCHUNK) {
            int lz  = c / 150;  int r2 = c - lz * 150;   // 150 = RYH*RXW/4
            int ly  = r2 / 10;  int lxc = r2 - ly * 10;  // 10 = RXW/4
            int mz = min(max(Z0 - 3 + lz, 0), DD - 1);
            int my = min(max(Y0 - 3 + ly, 0), HH - 1);
            int mx = min(max(X0 - 4 + lxc * 4, 0), WW - 4);  // 16B-aligned
            const float* g = cb + (mz * HH + my) * WW + mx;
            __builtin_amdgcn_global_load_lds(
                (gas_ptr)g, (las_ptr)(sbuf + 4 * c), 16, 0, 0);
        }
    }
}

// Trilinear sample of the single-channel staged region.
// INTERIOR: the whole region lies strictly inside the volume, so the
// boundary zero-weight masks are provably always-pass — skip them.
template<bool INTERIOR>
__device__ __forceinline__ float sample_lds(
    const float* __restrict__ sbuf,
    float lx, float ly, float lz, int rx0, int ry0, int rz0)
{
    float xf = floorf(lx), yf = floorf(ly), zf = floorf(lz);
    float fx = lx - xf, fy = ly - yf, fz = lz - zf;
    int ix = (int)xf, iy = (int)yf, iz = (int)zf;

    float wx0, wx1, wy0, wy1, wz0, wz1;
    if (INTERIOR) {
        wx0 = 1.0f - fx; wx1 = fx;
        wy0 = 1.0f - fy; wy1 = fy;
        wz0 = 1.0f - fz; wz1 = fz;
    } else {
        int vx0 = ix + rx0, vy0 = iy + ry0, vz0 = iz + rz0;
        wx0 = (vx0 >= 0  && vx0 < WW)     ? (1.0f - fx) : 0.0f;
        wx1 = (vx0 >= -1 && vx0 < WW - 1) ? fx          : 0.0f;
        wy0 = (vy0 >= 0  && vy0 < HH)     ? (1.0f - fy) : 0.0f;
        wy1 = (vy0 >= -1 && vy0 < HH - 1) ? fy          : 0.0f;
        wz0 = (vz0 >= 0  && vz0 < DD)     ? (1.0f - fz) : 0.0f;
        wz1 = (vz0 >= -1 && vz0 < DD - 1) ? fz          : 0.0f;
    }

    const float* pB = sbuf + (iz * RYH + iy) * RXW + ix;
    // Adjacent x0/x1 pairs -> ds_read2_b32.
    float A00 = pB[0],        B00 = pB[1];
    float A01 = pB[RXW],      B01 = pB[RXW + 1];
    const float* pC = pB + RYH * RXW;
    float A10 = pC[0],        B10 = pC[1];
    float A11 = pC[RXW],      B11 = pC[RXW + 1];

    float c00 = wx0 * A00 + wx1 * B00;
    float c01 = wx0 * A01 + wx1 * B01;
    float c10 = wx0 * A10 + wx1 * B10;
    float c11 = wx0 * A11 + wx1 * B11;
    float m0  = wy0 * c00 + wy1 * c01;
    float m1  = wy0 * c10 + wy1 * c11;
    return wz0 * m0 + wz1 * m1;
}

struct Geo {
    int X0, Y0, Z0;
    int x, y, z;          // this thread's global coords (x = first of 2)
    bool interior;        // region strictly inside the volume
    const float* sb;      // src channel-0 base for this batch
    const float* fp;      // flow pointer for this thread
    float* op;            // out pointer (channel 0) for this thread
};

__device__ __forceinline__ Geo decode_tile(
    int tl, const float* src, const float* flow, float* out,
    int xi, int yl, int zl)
{
    Geo g;
    int tx = tl % NTX;  int t2 = tl / NTX;
    int ty = t2 % NTY;  int t3 = t2 / NTY;
    int tz = t3 % NTZ;  int b  = t3 / NTZ;
    g.X0 = tx * TX; g.Y0 = ty * TY; g.Z0 = tz * TZ;
    g.interior = (tx >= 1) & (tx <= 3) &
                 (ty >= 1) & (ty <= 22) &
                 (tz >= 1) & (tz <= 18);
    g.x = g.X0 + xi; g.y = g.Y0 + yl; g.z = g.Z0 + zl;
    int go = (g.z * HH + g.y) * WW + g.x;
    g.sb = src + b * NC * SP;
    g.fp = flow + b * 3 * SP + go;
    g.op = out + b * NC * SP + go;
    return g;
}

// Compute 2 samples for one channel from LDS and store them.
template<bool INTERIOR>
__device__ __forceinline__ void compute_store(
    const float* __restrict__ sbuf, const Geo& g, int cofs,   // 0 or SP
    v2f dxv, v2f dyv, v2f dzv, int xi, int yl, int zl)
{
    const int rx0 = g.X0 - 4, ry0 = g.Y0 - 3, rz0 = g.Z0 - 3;
    float a[2];
    #pragma unroll
    for (int j = 0; j < 2; ++j) {
        float dx = dxv[j], dy = dyv[j], dz = dzv[j];
        bool inH = (dx >= -4.0f) & (dx < 4.0f) &
                   (dy >= -3.0f) & (dy < 4.0f) &
                   (dz >= -3.0f) & (dz < 4.0f);
        if (inH) {
            float lx = (float)(xi + j + 4) + dx;
            float ly = (float)(yl + 3) + dy;
            float lz = (float)(zl + 3) + dz;
            a[j] = sample_lds<INTERIOR>(sbuf, lx, ly, lz, rx0, ry0, rz0);
        } else {
            a[j] = sample_global1(g.sb + cofs, g.x + j, g.y, g.z, dx, dy, dz);
        }
    }
    v2f o = {a[0], a[1]};
    st2_nt(g.op + cofs, o);
}

// 2 blocks/CU x 16 waves = 32 waves/CU; 8 waves/SIMD -> VGPR cap 64
// (natural ~40-52: no spill — watch WRITE_SIZE == 76,800 KB).
__global__ __launch_bounds__(NTHR, 8) void st_warp_kernel(
    const float* __restrict__ src,   // [B, C, D, H, W]
    const float* __restrict__ flow,  // [B, 3, D, H, W]
    float* __restrict__ out)         // [B, C, D, H, W]
{
    __shared__ float sA[REGC];   // channel-0 buffer
    __shared__ float sB[REGC];   // channel-1 buffer   (72,000 B total)

    int u    = blockIdx.x;
    int xcd  = u & 7;            // XCD-chunked tile ranges
    int slot = u >> 3;           // 0..63 within XCD
    int tid  = threadIdx.x;

    int xi = (tid & 15) << 1;    // x: 0..30 step 2
    int rr = tid >> 4;           // 0..63
    int yl = rr & 7, zl = rr >> 3;   // y 0..7, z 0..7

    // Tiles for this block: tl0, tl0+64, ... (9 or 10 tiles).
    int nt = (TPX - slot + SLOTS - 1) / SLOTS;
    int tl = xcd * TPX + slot;

    // ---- Prologue: stage tile 0 / c0, load its flow ----
    Geo g = decode_tile(tl, src, flow, out, xi, yl, zl);
    stage_channel(g.sb, g.X0, g.Y0, g.Z0, tid, sA);
    v2f dxv = ld2_nt(g.fp);
    v2f dyv = ld2_nt(g.fp + SP);
    v2f dzv = ld2_nt(g.fp + 2 * SP);

    for (int t = 0; t < nt; ++t) {
        __syncthreads();     // drains vmcnt: sA(c0,t) staged; sB free

        // Issue c1 staging, then compute c0 — stage hides under compute.
        stage_channel(g.sb + SP, g.X0, g.Y0, g.Z0, tid, sB);
        if (g.interior)
            compute_store<true >(sA, g, 0, dxv, dyv, dzv, xi, yl, zl);
        else
            compute_store<false>(sA, g, 0, dxv, dyv, dzv, xi, yl, zl);

        __syncthreads();     // drains vmcnt: sB(c1,t) staged; sA free

        // Issue next tile's c0 staging + flow loads, then compute c1.
        bool more = (t + 1 < nt);          // block-uniform
        Geo gn = g;
        v2f nxv = dxv, nyv = dyv, nzv = dzv;
        if (more) {
            gn = decode_tile(tl + (t + 1) * SLOTS, src, flow, out, xi, yl, zl);
            stage_channel(gn.sb, gn.X0, gn.Y0, gn.Z0, tid, sA);
            nxv = ld2_nt(gn.fp);
            nyv = ld2_nt(gn.fp + SP);
            nzv = ld2_nt(gn.fp + 2 * SP);
        }
        if (g.interior)
            compute_store<true >(sB, g, SP, dxv, dyv, dzv, xi, yl, zl);
        else
            compute_store<false>(sB, g, SP, dxv, dyv, dzv, xi, yl, zl);

        g = gn; dxv = nxv; dyv = nyv; dzv = nzv;
    }
}

extern "C" void kernel_launch(void* const* d_in, const int* in_sizes, int n_in,
                              void* d_out, int out_size, void* d_ws, size_t ws_size,
                              hipStream_t stream) {
    const float* src  = (const float*)d_in[0];
    const float* flow = (const float*)d_in[1];
    float* out = (float*)d_out;

    st_warp_kernel<<<NBLK, NTHR, 0, stream>>>(src, flow, out);
}